// Round 1
// baseline (392.448 us; speedup 1.0000x reference)
//
#include <hip/hip_runtime.h>

typedef float  f32x4  __attribute__((ext_vector_type(4)));
typedef __bf16 bf16x8 __attribute__((ext_vector_type(8)));
typedef unsigned short u16x8 __attribute__((ext_vector_type(8)));

__device__ __forceinline__ unsigned short f2bf(float f) {
    unsigned u = __builtin_bit_cast(unsigned, f);
    unsigned r = u + 0x7FFFu + ((u >> 16) & 1u);   // round-to-nearest-even
    return (unsigned short)(r >> 16);
}

__device__ __forceinline__ f32x4 mfma16(u16x8 a, u16x8 b, f32x4 c) {
    return __builtin_amdgcn_mfma_f32_16x16x32_bf16(
        __builtin_bit_cast(bf16x8, a), __builtin_bit_cast(bf16x8, b), c, 0, 0, 0);
}

// ---------------- cast fp32 -> bf16 (8 elems / thread) ----------------
__global__ __launch_bounds__(256) void cast_bf16(const float* __restrict__ in,
                                                 unsigned short* __restrict__ out) {
    int t = blockIdx.x * 256 + threadIdx.x;          // 1,048,576 threads x 8 elems
    const float* p = in + (size_t)t * 8;
    f32x4 a = *(const f32x4*)p;
    f32x4 b = *(const f32x4*)(p + 4);
    u16x8 o;
    o[0] = f2bf(a[0]); o[1] = f2bf(a[1]); o[2] = f2bf(a[2]); o[3] = f2bf(a[3]);
    o[4] = f2bf(b[0]); o[5] = f2bf(b[1]); o[6] = f2bf(b[2]); o[7] = f2bf(b[3]);
    *(u16x8*)(out + (size_t)t * 8) = o;
}

// -------- cast + transpose 1024x1024 fp32 W[k][n] -> bf16 Wt[n][k] --------
__global__ __launch_bounds__(256) void cast_transpose_k(const float* __restrict__ W,
                                                        unsigned short* __restrict__ Wt) {
    int idx = blockIdx.x * 256 + threadIdx.x;        // 131,072 threads
    int n  = idx >> 7;                               // 0..1023
    int k0 = (idx & 127) << 3;                       // 0..1016
    u16x8 o;
#pragma unroll
    for (int e = 0; e < 8; ++e) o[e] = f2bf(W[(size_t)(k0 + e) * 1024 + n]);
    *(u16x8*)&Wt[(size_t)n * 1024 + k0] = o;
}

// ---------------- GEMM: C[M=8192][1024] = A[8192][1024] * Bt[1024][1024]^T ----------------
// A row-major [M][K] bf16, Bt row-major [N][K] bf16 (i.e. B transposed).
template <bool OUT_BF16>
__global__ __launch_bounds__(256) void gemm_bt(const unsigned short* __restrict__ A,
                                               const unsigned short* __restrict__ Bt,
                                               void* __restrict__ Cout,
                                               const float* __restrict__ bias) {
    constexpr int K = 1024, NN = 1024;
    __shared__ unsigned short As[128][72];   // +8 pad: 144B rows, 16B aligned
    __shared__ unsigned short Bs[128][72];
    const int tid  = threadIdx.x;
    const int lane = tid & 63, wid = tid >> 6;
    const int wm = wid >> 1, wn = wid & 1;
    const int i = lane & 15, q8 = (lane >> 4) * 8;
    const int tm = blockIdx.y * 128, tn = blockIdx.x * 128;
    const int srow = tid >> 3, scol = (tid & 7) * 8;

    f32x4 acc[4][4] = {};

    for (int k0 = 0; k0 < K; k0 += 64) {
#pragma unroll
        for (int c = 0; c < 4; ++c) {
            int row = c * 32 + srow;
            u16x8 av = *(const u16x8*)&A [(size_t)(tm + row) * K + k0 + scol];
            u16x8 bv = *(const u16x8*)&Bt[(size_t)(tn + row) * K + k0 + scol];
            *(u16x8*)&As[row][scol] = av;
            *(u16x8*)&Bs[row][scol] = bv;
        }
        __syncthreads();
#pragma unroll
        for (int ks = 0; ks < 2; ++ks) {
            u16x8 af[4], bf[4];
#pragma unroll
            for (int m = 0; m < 4; ++m) af[m] = *(const u16x8*)&As[wm * 64 + m * 16 + i][ks * 32 + q8];
#pragma unroll
            for (int n = 0; n < 4; ++n) bf[n] = *(const u16x8*)&Bs[wn * 64 + n * 16 + i][ks * 32 + q8];
#pragma unroll
            for (int m = 0; m < 4; ++m)
#pragma unroll
                for (int n = 0; n < 4; ++n)
                    acc[m][n] = mfma16(af[m], bf[n], acc[m][n]);
        }
        __syncthreads();
    }

    const int r0 = (lane >> 4) * 4;
#pragma unroll
    for (int n = 0; n < 4; ++n) {
        int col = tn + wn * 64 + n * 16 + i;
        float bv = 0.f;
        if constexpr (!OUT_BF16) bv = bias[col];
#pragma unroll
        for (int m = 0; m < 4; ++m) {
            int rowb = tm + wm * 64 + m * 16 + r0;
#pragma unroll
            for (int r = 0; r < 4; ++r) {
                if constexpr (OUT_BF16)
                    ((unsigned short*)Cout)[(size_t)(rowb + r) * NN + col] = f2bf(acc[m][n][r]);
                else
                    ((float*)Cout)[(size_t)(rowb + r) * NN + col] = acc[m][n][r] + bv;
            }
        }
    }
}

// ---------------- Flash attention, Q=K=V = qkv[b,:,h*64:(h+1)*64] ----------------
// grid: (32 q-tiles, 16 heads, 4 batch), 256 threads (4 waves x 16 q-rows).
__global__ __launch_bounds__(256) void flash_attn(const unsigned short* __restrict__ qkv,
                                                  unsigned short* __restrict__ attnout) {
    __shared__ unsigned short Ks[64][72];
    __shared__ unsigned short Vt[64][72];
    __shared__ unsigned short Pl[4][16][72];

    const int tid  = threadIdx.x;
    const int lane = tid & 63, wid = tid >> 6;
    const int i = lane & 15, qg = lane >> 4, q8 = qg * 8;
    const int b = blockIdx.z, h = blockIdx.y, q0 = blockIdx.x * 64;
    const size_t base = ((size_t)b * 2048) * 1024 + (size_t)h * 64;

    // Q fragments live in registers for the whole block
    u16x8 qf[2];
    {
        int row = q0 + wid * 16 + i;
#pragma unroll
        for (int ks = 0; ks < 2; ++ks)
            qf[ks] = *(const u16x8*)&qkv[base + (size_t)row * 1024 + ks * 32 + q8];
    }

    float m_run[4], l_run[4];
    f32x4 po[4] = {};
#pragma unroll
    for (int r = 0; r < 4; ++r) { m_run[r] = -1e30f; l_run[r] = 0.f; }

    for (int kt = 0; kt < 32; ++kt) {
        const int kv0 = kt * 64;
        // stage KV tile (K and V are the same data): Ks vectorized, Vt transposed
#pragma unroll
        for (int c = 0; c < 2; ++c) {
            int idx = c * 256 + tid;
            int row = idx >> 3, col = (idx & 7) * 8;
            u16x8 g = *(const u16x8*)&qkv[base + (size_t)(kv0 + row) * 1024 + col];
            *(u16x8*)&Ks[row][col] = g;
#pragma unroll
            for (int e = 0; e < 8; ++e) Vt[col + e][row] = g[e];
        }
        __syncthreads();

        // S = Q K^T * scale
        f32x4 s[4];
#pragma unroll
        for (int n = 0; n < 4; ++n) {
            f32x4 a = {};
#pragma unroll
            for (int ks = 0; ks < 2; ++ks) {
                u16x8 kf = *(const u16x8*)&Ks[n * 16 + i][ks * 32 + q8];
                a = mfma16(qf[ks], kf, a);
            }
            s[n] = a * 0.125f;
        }

        // online softmax, per q-row (reg r), reduce across the 16-lane col group
#pragma unroll
        for (int r = 0; r < 4; ++r) {
            float rm = fmaxf(fmaxf(s[0][r], s[1][r]), fmaxf(s[2][r], s[3][r]));
#pragma unroll
            for (int off = 1; off < 16; off <<= 1) rm = fmaxf(rm, __shfl_xor(rm, off));
            float mnew  = fmaxf(m_run[r], rm);
            float alpha = __expf(m_run[r] - mnew);
            m_run[r] = mnew;
            float psum = 0.f;
#pragma unroll
            for (int n = 0; n < 4; ++n) {
                float p = __expf(s[n][r] - mnew);
                s[n][r] = p;
                psum += p;
            }
#pragma unroll
            for (int off = 1; off < 16; off <<= 1) psum += __shfl_xor(psum, off);
            l_run[r] = l_run[r] * alpha + psum;
#pragma unroll
            for (int n = 0; n < 4; ++n) po[n][r] *= alpha;
        }

        // P (f32, S-layout) -> bf16 in per-wave LDS, A-fragment layout for PV
#pragma unroll
        for (int r = 0; r < 4; ++r)
#pragma unroll
            for (int n = 0; n < 4; ++n)
                Pl[wid][qg * 4 + r][n * 16 + i] = f2bf(s[n][r]);

        // O += P V
#pragma unroll
        for (int ks = 0; ks < 2; ++ks) {
            u16x8 pa = *(const u16x8*)&Pl[wid][i][ks * 32 + q8];
#pragma unroll
            for (int n = 0; n < 4; ++n) {
                u16x8 vf = *(const u16x8*)&Vt[n * 16 + i][ks * 32 + q8];
                po[n] = mfma16(pa, vf, po[n]);
            }
        }
        __syncthreads();
    }

    // normalize + write back into [B,N,H*D] bf16
#pragma unroll
    for (int r = 0; r < 4; ++r) {
        float inv = 1.f / l_run[r];
        int row = q0 + wid * 16 + qg * 4 + r;
#pragma unroll
        for (int n = 0; n < 4; ++n)
            attnout[base + (size_t)row * 1024 + n * 16 + i] = f2bf(po[n][r] * inv);
    }
}

extern "C" void kernel_launch(void* const* d_in, const int* in_sizes, int n_in,
                              void* d_out, int out_size, void* d_ws, size_t ws_size,
                              hipStream_t stream) {
    const float* x    = (const float*)d_in[0];
    const float* Wqkv = (const float*)d_in[1];
    const float* Wout = (const float*)d_in[2];
    const float* bout = (const float*)d_in[3];
    float* out = (float*)d_out;

    char* ws = (char*)d_ws;
    unsigned short* xb   = (unsigned short*)(ws);               // 16 MiB: x bf16, later reused as attn out
    unsigned short* qkvb = (unsigned short*)(ws + 16777216);    // 16 MiB: qkv bf16
    unsigned short* wqt  = (unsigned short*)(ws + 33554432);    // 2 MiB : W_qkv^T bf16
    unsigned short* wot  = (unsigned short*)(ws + 35651584);    // 2 MiB : W_out^T bf16

    cast_bf16<<<4096, 256, 0, stream>>>(x, xb);
    cast_transpose_k<<<512, 256, 0, stream>>>(Wqkv, wqt);
    cast_transpose_k<<<512, 256, 0, stream>>>(Wout, wot);

    // qkv = x @ W_qkv   (bf16 out)
    gemm_bt<true><<<dim3(8, 64), 256, 0, stream>>>(xb, wqt, qkvb, nullptr);

    // attention (writes bf16 into xb region, fully overwritten)
    flash_attn<<<dim3(32, 16, 4), 256, 0, stream>>>(qkvb, xb);

    // out = attn @ W_out + b   (fp32 out)
    gemm_bt<false><<<dim3(8, 64), 256, 0, stream>>>(xb, wot, out, bout);
}